// Round 10
// baseline (234.480 us; speedup 1.0000x reference)
//
#include <hip/hip_runtime.h>

#define N_NODES 16384
#define N_EDGES 32768
#define D 128
#define EDGE_DIM 10
#define KH 32          // edge-hidden dim
#define BM 128         // edges per msg block (mt=8, split-K)
#define XST2 72        // msg Xs row stride (f16): 144B, 16B-aligned rows
#define XST 136        // node_update Xs pad
#define NBL 16         // nodes per node_update block (1024 blocks)

typedef _Float16 f16;
typedef _Float16 f16x4 __attribute__((ext_vector_type(4)));
typedef _Float16 f16x8 __attribute__((ext_vector_type(8)));
typedef float f32x4 __attribute__((ext_vector_type(4)));

// inline-asm 16B global load: pinned VGPR dest, vmcnt controlled manually
__device__ __forceinline__ void ld16(f16x8 &d, const f16* p) {
  asm volatile("global_load_dwordx4 %0, %1, off" : "=v"(d) : "v"(p) : "memory");
}

// ---- fused: deg count (y=0) + 6 pack jobs (y=1..6) + edge MLP (y=7,8) ----
__global__ __launch_bounds__(256) void deg_pack_kernel(
    const int* __restrict__ ei, int* __restrict__ deg,
    const float* __restrict__ w1l2, const float* __restrict__ w2l2,
    const float* __restrict__ b1l2, const float* __restrict__ b2l2,
    const float* __restrict__ rt1, const float* __restrict__ rt2,
    f16* __restrict__ Bp1, f16* __restrict__ Bp2,
    f16* __restrict__ Rp1, f16* __restrict__ Rp2,
    const float* __restrict__ ea,
    const float* __restrict__ w1l1, const float* __restrict__ b1l1,
    const float* __restrict__ w2l1, const float* __restrict__ b2l1,
    f16* __restrict__ h1, f16* __restrict__ h2) {
  int y = blockIdx.y;
  if (y == 0) {
    int e = blockIdx.x * 256 + threadIdx.x;
    if (e < N_EDGES) atomicAdd(&deg[ei[N_EDGES + e]], 1);
    return;
  }
  if (y >= 7) {
    // edge MLP in EDGE order (contiguous ea reads, contiguous h writes)
    int e = blockIdx.x * 256 + threadIdx.x;   // 128 blocks cover 32768
    const float* l1w = (y == 8) ? w2l1 : w1l1;
    const float* l1b = (y == 8) ? b2l1 : b1l1;
    f16* h = (y == 8) ? h2 : h1;
    float a[EDGE_DIM];
#pragma unroll
    for (int d = 0; d < EDGE_DIM; d++) a[d] = ea[e * EDGE_DIM + d];
    f16 hv[KH];
#pragma unroll
    for (int k = 0; k < KH; k++) {
      float acc = l1b[k];
#pragma unroll
      for (int d = 0; d < EDGE_DIM; d++) acc += a[d] * l1w[d * KH + k];
      hv[k] = (f16)fmaxf(acc, 0.0f);
    }
    f16x8* dst = (f16x8*)(h + (size_t)e * KH);
#pragma unroll
    for (int c = 0; c < 4; c++) dst[c] = *(f16x8*)&hv[c * 8];
    return;
  }
  if (blockIdx.x >= D * D / 256) return;
  int t = blockIdx.x * 256 + threadIdx.x;   // 0..16383
  int j = y - 1;
  if (j < 2) {
    const float* l2w = j ? w2l2 : w1l2;
    f16* Bp = j ? Bp2 : Bp1;
    f16 tmp[KH];
#pragma unroll
    for (int k = 0; k < KH; k++) tmp[k] = (f16)l2w[(size_t)k * (D * D) + t];
    f16x8* dst = (f16x8*)(Bp + (size_t)t * KH);
#pragma unroll
    for (int c = 0; c < 4; c++) dst[c] = *(f16x8*)&tmp[c * 8];
  } else {
    const float* src = (j == 2) ? b1l2 : (j == 3) ? b2l2 : (j == 4) ? rt1 : rt2;
    f16* dst = (j == 2) ? (Bp1 + (size_t)D * D * KH)
             : (j == 3) ? (Bp2 + (size_t)D * D * KH)
             : (j == 4) ? Rp1 : Rp2;
    int i = t >> 7, o = t & 127;
    dst[((size_t)(i >> 5) * D + o) * KH + (i & 31)] = (f16)src[t];
  }
}

// wave-shuffle scan: 1 barrier instead of 20
__global__ __launch_bounds__(1024) void scan_kernel(
    const int* __restrict__ deg, int* __restrict__ rs, int* __restrict__ fill) {
  __shared__ int wsum[16];
  int t = threadIdx.x;
  int lane = t & 63, wid = t >> 6;
  int base = t * 16;
  int loc[16], s = 0;
#pragma unroll
  for (int j = 0; j < 16; j++) { loc[j] = deg[base + j]; s += loc[j]; }
  // inclusive scan of s across the wave
  int v = s;
#pragma unroll
  for (int off = 1; off < 64; off <<= 1) {
    int u = __shfl_up(v, off);
    if (lane >= off) v += u;
  }
  if (lane == 63) wsum[wid] = v;
  __syncthreads();
  int woff = 0;
#pragma unroll
  for (int j = 0; j < 16; j++) woff += (j < wid) ? wsum[j] : 0;
  int run = woff + (v - s);   // exclusive prefix for this thread's 16-chunk
#pragma unroll
  for (int j = 0; j < 16; j++) {
    rs[base + j] = run; fill[base + j] = run; run += loc[j];
  }
  if (t == 1023) rs[N_NODES] = run;
}

// light scatter: assign sorted position only (no heavy compute after atomic)
__global__ __launch_bounds__(256) void scatter_kernel(
    const int* __restrict__ ei, int* __restrict__ fill,
    int* __restrict__ perm, int* __restrict__ srcs) {
  int e = blockIdx.x * blockDim.x + threadIdx.x;
  if (e < N_EDGES) {
    int pos = atomicAdd(&fill[ei[N_EDGES + e]], 1);
    perm[pos] = e;
    srcs[pos] = ei[e];
  }
}

// msg GEMM: BM=128, mt=8, nt=2, split-K, counted-vmcnt asm pipeline
// (3 batches / 24 loads in flight), setprio. Prologue batches issued
// BEFORE the staging barrier: their L2 latency hides under the staging
// store + barrier drain (loop's first waits become no-ops, pipeline
// refills from loop issues).
__global__ __launch_bounds__(256, 2) void msg_mfma_kernel(
    const float* __restrict__ xin, const f16* __restrict__ hf,
    const f16* __restrict__ Bp, const int* __restrict__ srcs,
    const int* __restrict__ perm,
    f16* __restrict__ msgfA, f16* __restrict__ msgfB) {
  __shared__ f16 Xs[BM][XST2];  // 18.4 KB (half of x cols, 128 edges)
  __shared__ f16 Hs[BM][KH];    // 8 KB
  int t = threadIdx.x;
  int e0 = blockIdx.x * BM;
  int y  = blockIdx.y;
  f16* msgf = y ? msgfB : msgfA;

  int L = t & 63, w = t >> 6;
  int quad = L >> 4, lm = L & 15;
  int n0 = w * 32;

  const f16* bl = Bp + ((size_t)(y * 64) * D + n0 + lm) * KH + quad * 8;
  const size_t istr = (size_t)D * KH;    // f16 stride per i

  f16x8 bufA[4][2], bufB[4][2], bufC[4][2];

  // issue one 4-i batch = 8 asm loads (pinned dests, untracked by compiler)
  auto issueB = [&](f16x8 (&buf)[4][2], int basei) {
#pragma unroll
    for (int jj = 0; jj < 4; jj++) {
      const f16* bi = bl + (size_t)(basei + jj) * istr;
      ld16(buf[jj][0], bi);
      ld16(buf[jj][1], bi + 16 * KH);
    }
  };

  // prologue: 3 batches in flight BEFORE staging stores/barrier
  issueB(bufA, 0);               // batch 0 (i  0.. 3)
  issueB(bufB, 4);               // batch 1 (i  4.. 7)
  issueB(bufC, 8);               // batch 2 (i  8..11)

  {
    int r = t >> 1, q = t & 1;     // 2 threads per edge row
    int ep = perm[e0 + r];
    const f16x8* hsrc = (const f16x8*)(hf + (size_t)ep * KH + q * 16);
    *(f16x8*)&Hs[r][q * 16]     = hsrc[0];
    *(f16x8*)&Hs[r][q * 16 + 8] = hsrc[1];
    int s = srcs[e0 + r];
    const float4* src = (const float4*)(xin + (size_t)s * D + y * 64 + q * 32);
    f16* dst = &Xs[r][q * 32];
#pragma unroll
    for (int c = 0; c < 8; c++) {
      float4 v = src[c];
      f16x4 h4 = {(f16)v.x, (f16)v.y, (f16)v.z, (f16)v.w};
      *(f16x4*)(dst + c * 4) = h4;
    }
  }

  f32x4 acc[8][2];
#pragma unroll
  for (int mt = 0; mt < 8; mt++)
#pragma unroll
    for (int nt = 0; nt < 2; nt++)
      acc[mt][nt] = (f32x4){0.f, 0.f, 0.f, 0.f};

  // counted wait: keep 16 loads (2 batches) in flight; oldest batch retired
  auto wait16 = [&]() {
    asm volatile("s_waitcnt vmcnt(16)" ::: "memory");
    __builtin_amdgcn_sched_barrier(0);
  };
  auto wait8 = [&]() {
    asm volatile("s_waitcnt vmcnt(8)" ::: "memory");
    __builtin_amdgcn_sched_barrier(0);
  };
  auto wait0 = [&]() {
    asm volatile("s_waitcnt vmcnt(0)" ::: "memory");
    __builtin_amdgcn_sched_barrier(0);
  };

  f16x8 hreg[8];

  auto compute = [&](f16x8 (&buf)[4][2], int ig) {
    f16x4 xv[8];
#pragma unroll
    for (int mt = 0; mt < 8; mt++)
      xv[mt] = *(const f16x4*)&Xs[mt * 16 + lm][ig];
    __builtin_amdgcn_s_setprio(1);
#pragma unroll
    for (int jj = 0; jj < 4; jj++) {
#pragma unroll
      for (int mt = 0; mt < 8; mt++) {
        f16 xs = xv[mt][jj];
        f16x8 xb = {xs, xs, xs, xs, xs, xs, xs, xs};
        f16x8 a = hreg[mt] * xb;
        acc[mt][0] = __builtin_amdgcn_mfma_f32_16x16x32_f16(a, buf[jj][0], acc[mt][0], 0, 0, 0);
        acc[mt][1] = __builtin_amdgcn_mfma_f32_16x16x32_f16(a, buf[jj][1], acc[mt][1], 0, 0, 0);
      }
    }
    __builtin_amdgcn_s_setprio(0);
  };

  __syncthreads();               // Xs/Hs ready; ALL loads (incl. batches 0-2) drained

#pragma unroll
  for (int mt = 0; mt < 8; mt++)
    hreg[mt] = *(const f16x8*)&Hs[mt * 16 + lm][quad * 8];

  // batches 0..15 (i = 4*batch); loop computes 0..11, issues 3..14
#pragma unroll 1
  for (int gi = 0; gi < 4; gi++) {
    wait16();
    compute(bufA, 12 * gi);
    issueB(bufA, 12 * gi + 12);        // batch 3gi+3
    wait16();
    compute(bufB, 12 * gi + 4);
    issueB(bufB, 12 * gi + 16);        // batch 3gi+4
    wait16();
    compute(bufC, 12 * gi + 8);
    issueB(bufC, 12 * gi + 20);        // batch 3gi+5, max basei = 56 (batch 14)
  }
  wait16();
  compute(bufA, 48);             // batch 12
  issueB(bufA, 60);              // batch 15 (last)
  wait16();
  compute(bufB, 52);             // batch 13
  wait8();
  compute(bufC, 56);             // batch 14
  wait0();
  compute(bufA, 60);             // batch 15 -- all loads drained

  // bias fold: this half handles ig2 = 2y, 2y+1 (uses only this half's x)
  {
    const f16* bb = Bp + (size_t)D * D * KH;
#pragma unroll
    for (int g2 = 0; g2 < 2; g2++) {
      int ig2 = 2 * y + g2;
      const f16* b2l = bb + ((size_t)ig2 * D + n0 + lm) * KH + quad * 8;
      f16x8 b0 = *(const f16x8*)b2l;
      f16x8 b1 = *(const f16x8*)(b2l + 16 * KH);
      int lc = g2 * 32 + quad * 8;
#pragma unroll
      for (int mt = 0; mt < 8; mt++) {
        f16x8 a = *(const f16x8*)&Xs[mt * 16 + lm][lc];
        acc[mt][0] = __builtin_amdgcn_mfma_f32_16x16x32_f16(a, b0, acc[mt][0], 0, 0, 0);
        acc[mt][1] = __builtin_amdgcn_mfma_f32_16x16x32_f16(a, b1, acc[mt][1], 0, 0, 0);
      }
    }
  }

  // C/D: col = lane&15 (+nt*16), row = quad*4 + reg
#pragma unroll
  for (int mt = 0; mt < 8; mt++)
#pragma unroll
    for (int r = 0; r < 4; r++) {
      f16* mg = msgf + (size_t)(e0 + mt * 16 + quad * 4 + r) * D + n0 + lm;
      mg[0]  = (f16)acc[mt][0][r];
      mg[16] = (f16)acc[mt][1][r];
    }
}

// node update: out = (relu?) bias + segmean(msgA+msgB) + x@root (f16 MFMA)
// NBL=16 -> 1024 blocks (4/CU); segmean has 1-deep load-ahead pipeline.
__global__ __launch_bounds__(256) void node_update_kernel(
    const float* __restrict__ xin, const f16* __restrict__ msgA,
    const f16* __restrict__ msgB, const int* __restrict__ rs,
    const f16* __restrict__ Rp, const float* __restrict__ bias,
    float* __restrict__ out, int do_relu) {
  __shared__ f16 Xs[NBL][XST];   // 4.3 KB
  __shared__ float Sls[NBL][D];  // 8.2 KB
  int t = threadIdx.x;
  int nb = blockIdx.x * NBL;

  {
    int r = t >> 4, q = t & 15;  // 16 threads per node row, 8 f32 each
    const float4* src = (const float4*)(xin + (size_t)(nb + r) * D + q * 8);
    f16* dst = &Xs[r][q * 8];
#pragma unroll
    for (int c = 0; c < 2; c++) {
      float4 v = src[c];
      f16x4 h4 = {(f16)v.x, (f16)v.y, (f16)v.z, (f16)v.w};
      *(f16x4*)(dst + c * 4) = h4;
    }
  }
  __syncthreads();

  // segment mean over contiguous sorted msg rows (load-ahead pipeline)
  {
    int nl = t >> 4, o0 = (t & 15) * 8;
    int n = nb + nl;
    int a = rs[n], b = rs[n + 1];
    float sum[8];
#pragma unroll
    for (int j = 0; j < 8; j++) sum[j] = 0.f;
    f16x8 pa, pb;
    if (a < b) {
      pa = *(const f16x8*)(msgA + (size_t)a * D + o0);
      pb = *(const f16x8*)(msgB + (size_t)a * D + o0);
    }
    for (int r = a; r < b; r++) {
      f16x8 ca = pa, cb = pb;
      if (r + 1 < b) {
        pa = *(const f16x8*)(msgA + (size_t)(r + 1) * D + o0);
        pb = *(const f16x8*)(msgB + (size_t)(r + 1) * D + o0);
      }
#pragma unroll
      for (int j = 0; j < 8; j++) sum[j] += (float)ca[j] + (float)cb[j];
    }
    float inv = 1.0f / (float)max(b - a, 1);
#pragma unroll
    for (int j = 0; j < 8; j++) Sls[nl][o0 + j] = sum[j] * inv;
  }
  __syncthreads();

  // x@root via MFMA, K=128 (4 slabs), 16 rows (mt=1)
  int L = t & 63, w = t >> 6;
  int quad = L >> 4, lm = L & 15;
  int n0 = w * 32;
  f32x4 acc[2];
  acc[0] = (f32x4){0.f, 0.f, 0.f, 0.f};
  acc[1] = (f32x4){0.f, 0.f, 0.f, 0.f};
#pragma unroll
  for (int s4 = 0; s4 < 4; s4++) {
    const f16* b2l = Rp + ((size_t)s4 * D + n0 + lm) * KH + quad * 8;
    f16x8 b0 = *(const f16x8*)b2l;
    f16x8 b1 = *(const f16x8*)(b2l + 16 * KH);
    f16x8 a = *(const f16x8*)&Xs[lm][s4 * 32 + quad * 8];
    acc[0] = __builtin_amdgcn_mfma_f32_16x16x32_f16(a, b0, acc[0], 0, 0, 0);
    acc[1] = __builtin_amdgcn_mfma_f32_16x16x32_f16(a, b1, acc[1], 0, 0, 0);
  }
#pragma unroll
  for (int r = 0; r < 4; r++) {
    Sls[quad * 4 + r][n0 + lm] += acc[0][r];
    Sls[quad * 4 + r][n0 + 16 + lm] += acc[1][r];
  }
  __syncthreads();

  {
    int o = t & 127, g = t >> 7;   // g = 0..1, 8 rows each
    float bo = bias[o];
    for (int q = g * 8; q < g * 8 + 8; q++) {
      float v = bo + Sls[q][o];
      out[(size_t)(nb + q) * D + o] = do_relu ? fmaxf(v, 0.0f) : v;
    }
  }
}

extern "C" void kernel_launch(void* const* d_in, const int* in_sizes, int n_in,
                              void* d_out, int out_size, void* d_ws, size_t ws_size,
                              hipStream_t stream) {
  const float* x      = (const float*)d_in[0];
  const int*   ei     = (const int*)d_in[1];
  const float* ea     = (const float*)d_in[2];
  const float* w1_l1  = (const float*)d_in[3];
  const float* b1_l1  = (const float*)d_in[4];
  const float* w1_l2  = (const float*)d_in[5];
  const float* b1_l2  = (const float*)d_in[6];
  const float* w1_rt  = (const float*)d_in[7];
  const float* b1     = (const float*)d_in[8];
  const float* w2_l1  = (const float*)d_in[9];
  const float* b2_l1  = (const float*)d_in[10];
  const float* w2_l2  = (const float*)d_in[11];
  const float* b2_l2  = (const float*)d_in[12];
  const float* w2_rt  = (const float*)d_in[13];
  const float* b2     = (const float*)d_in[14];
  float* out = (float*)d_out;

  const size_t BPSZ = (size_t)D * D * KH + (size_t)D * D + 32768;
  f16* h1f = (f16*)d_ws;
  f16* h2f = h1f + (size_t)N_EDGES * KH;
  f16* Bp1 = h2f + (size_t)N_EDGES * KH;
  f16* Bp2 = Bp1 + BPSZ;
  f16* Rp1 = Bp2 + BPSZ;
  f16* Rp2 = Rp1 + (size_t)D * D;
  int* deg  = (int*)(Rp2 + (size_t)D * D);
  int* rs   = deg + N_NODES;
  int* fill = rs + N_NODES + 128;
  int* perm = fill + N_NODES;
  int* srcs = perm + N_EDGES;
  f16* msgA = (f16*)(srcs + N_EDGES);      // E*D f16 (8.4 MB)
  f16* msgB = msgA + (size_t)N_EDGES * D;  // E*D f16 (8.4 MB)

  hipMemsetAsync(deg, 0, N_NODES * sizeof(int), stream);
  deg_pack_kernel<<<dim3(N_EDGES / 256, 9), 256, 0, stream>>>(
      ei, deg, w1_l2, w2_l2, b1_l2, b2_l2, w1_rt, w2_rt, Bp1, Bp2, Rp1, Rp2,
      ea, w1_l1, b1_l1, w2_l1, b2_l1, h1f, h2f);
  scan_kernel<<<1, 1024, 0, stream>>>(deg, rs, fill);
  scatter_kernel<<<N_EDGES / 256, 256, 0, stream>>>(ei, fill, perm, srcs);

  // layer 1
  msg_mfma_kernel<<<dim3(N_EDGES / BM, 2), 256, 0, stream>>>(x, h1f, Bp1, srcs, perm, msgA, msgB);
  node_update_kernel<<<N_NODES / NBL, 256, 0, stream>>>(x, msgA, msgB, rs, Rp1, b1, out, 1);
  // layer 2
  msg_mfma_kernel<<<dim3(N_EDGES / BM, 2), 256, 0, stream>>>(out, h2f, Bp2, srcs, perm, msgA, msgB);
  node_update_kernel<<<N_NODES / NBL, 256, 0, stream>>>(out, msgA, msgB, rs, Rp2, b2, out, 1);
  // layer 3
  msg_mfma_kernel<<<dim3(N_EDGES / BM, 2), 256, 0, stream>>>(out, h2f, Bp2, srcs, perm, msgA, msgB);
  node_update_kernel<<<N_NODES / NBL, 256, 0, stream>>>(out, msgA, msgB, rs, Rp2, b2, out, 0);
}

// Round 11
// 229.336 us; speedup vs baseline: 1.0224x; 1.0224x over previous
//
#include <hip/hip_runtime.h>

#define N_NODES 16384
#define N_EDGES 32768
#define D 128
#define EDGE_DIM 10
#define KH 32          // edge-hidden dim
#define BM 128         // edges per msg block (mt=8, split-K)
#define XST2 72        // msg Xs row stride (f16): 144B, 16B-aligned rows
#define XST 136        // node_update Xs pad
#define NBL 16         // nodes per node_update block (1024 blocks)

typedef _Float16 f16;
typedef _Float16 f16x4 __attribute__((ext_vector_type(4)));
typedef _Float16 f16x8 __attribute__((ext_vector_type(8)));
typedef float f32x4 __attribute__((ext_vector_type(4)));

// inline-asm 16B global load: pinned VGPR dest, vmcnt controlled manually
__device__ __forceinline__ void ld16(f16x8 &d, const f16* p) {
  asm volatile("global_load_dwordx4 %0, %1, off" : "=v"(d) : "v"(p) : "memory");
}

// ---- fused: deg count (y=0) + 6 pack jobs (y=1..6) + edge MLP (y=7,8) ----
__global__ __launch_bounds__(256) void deg_pack_kernel(
    const int* __restrict__ ei, int* __restrict__ deg,
    const float* __restrict__ w1l2, const float* __restrict__ w2l2,
    const float* __restrict__ b1l2, const float* __restrict__ b2l2,
    const float* __restrict__ rt1, const float* __restrict__ rt2,
    f16* __restrict__ Bp1, f16* __restrict__ Bp2,
    f16* __restrict__ Rp1, f16* __restrict__ Rp2,
    const float* __restrict__ ea,
    const float* __restrict__ w1l1, const float* __restrict__ b1l1,
    const float* __restrict__ w2l1, const float* __restrict__ b2l1,
    f16* __restrict__ h1, f16* __restrict__ h2) {
  int y = blockIdx.y;
  if (y == 0) {
    int e = blockIdx.x * 256 + threadIdx.x;
    if (e < N_EDGES) atomicAdd(&deg[ei[N_EDGES + e]], 1);
    return;
  }
  if (y >= 7) {
    // edge MLP in EDGE order (contiguous ea reads, contiguous h writes)
    int e = blockIdx.x * 256 + threadIdx.x;   // 128 blocks cover 32768
    const float* l1w = (y == 8) ? w2l1 : w1l1;
    const float* l1b = (y == 8) ? b2l1 : b1l1;
    f16* h = (y == 8) ? h2 : h1;
    float a[EDGE_DIM];
#pragma unroll
    for (int d = 0; d < EDGE_DIM; d++) a[d] = ea[e * EDGE_DIM + d];
    f16 hv[KH];
#pragma unroll
    for (int k = 0; k < KH; k++) {
      float acc = l1b[k];
#pragma unroll
      for (int d = 0; d < EDGE_DIM; d++) acc += a[d] * l1w[d * KH + k];
      hv[k] = (f16)fmaxf(acc, 0.0f);
    }
    f16x8* dst = (f16x8*)(h + (size_t)e * KH);
#pragma unroll
    for (int c = 0; c < 4; c++) dst[c] = *(f16x8*)&hv[c * 8];
    return;
  }
  if (blockIdx.x >= D * D / 256) return;
  int t = blockIdx.x * 256 + threadIdx.x;   // 0..16383
  int j = y - 1;
  if (j < 2) {
    const float* l2w = j ? w2l2 : w1l2;
    f16* Bp = j ? Bp2 : Bp1;
    f16 tmp[KH];
#pragma unroll
    for (int k = 0; k < KH; k++) tmp[k] = (f16)l2w[(size_t)k * (D * D) + t];
    f16x8* dst = (f16x8*)(Bp + (size_t)t * KH);
#pragma unroll
    for (int c = 0; c < 4; c++) dst[c] = *(f16x8*)&tmp[c * 8];
  } else {
    const float* src = (j == 2) ? b1l2 : (j == 3) ? b2l2 : (j == 4) ? rt1 : rt2;
    f16* dst = (j == 2) ? (Bp1 + (size_t)D * D * KH)
             : (j == 3) ? (Bp2 + (size_t)D * D * KH)
             : (j == 4) ? Rp1 : Rp2;
    int i = t >> 7, o = t & 127;
    dst[((size_t)(i >> 5) * D + o) * KH + (i & 31)] = (f16)src[t];
  }
}

// wave-shuffle scan: 1 barrier instead of 20 (correct, proven R10)
__global__ __launch_bounds__(1024) void scan_kernel(
    const int* __restrict__ deg, int* __restrict__ rs, int* __restrict__ fill) {
  __shared__ int wsum[16];
  int t = threadIdx.x;
  int lane = t & 63, wid = t >> 6;
  int base = t * 16;
  int loc[16], s = 0;
#pragma unroll
  for (int j = 0; j < 16; j++) { loc[j] = deg[base + j]; s += loc[j]; }
  // inclusive scan of s across the wave
  int v = s;
#pragma unroll
  for (int off = 1; off < 64; off <<= 1) {
    int u = __shfl_up(v, off);
    if (lane >= off) v += u;
  }
  if (lane == 63) wsum[wid] = v;
  __syncthreads();
  int woff = 0;
#pragma unroll
  for (int j = 0; j < 16; j++) woff += (j < wid) ? wsum[j] : 0;
  int run = woff + (v - s);   // exclusive prefix for this thread's 16-chunk
#pragma unroll
  for (int j = 0; j < 16; j++) {
    rs[base + j] = run; fill[base + j] = run; run += loc[j];
  }
  if (t == 1023) rs[N_NODES] = run;
}

// light scatter: assign sorted position only (no heavy compute after atomic)
__global__ __launch_bounds__(256) void scatter_kernel(
    const int* __restrict__ ei, int* __restrict__ fill,
    int* __restrict__ perm, int* __restrict__ srcs) {
  int e = blockIdx.x * blockDim.x + threadIdx.x;
  if (e < N_EDGES) {
    int pos = atomicAdd(&fill[ei[N_EDGES + e]], 1);
    perm[pos] = e;
    srcs[pos] = ei[e];
  }
}

// msg GEMM (R9-proven ordering): BM=128, mt=8, nt=2, split-K, counted-vmcnt
// asm pipeline (3 batches / 24 loads in flight), setprio. Prologue batches
// issued AFTER the staging barrier -- issuing them earlier pollutes the
// compiler's vmcnt accounting for the staging gather and serializes it
// behind the B-prefetch (R10: -5 us).
__global__ __launch_bounds__(256, 2) void msg_mfma_kernel(
    const float* __restrict__ xin, const f16* __restrict__ hf,
    const f16* __restrict__ Bp, const int* __restrict__ srcs,
    const int* __restrict__ perm,
    f16* __restrict__ msgfA, f16* __restrict__ msgfB) {
  __shared__ f16 Xs[BM][XST2];  // 18.4 KB (half of x cols, 128 edges)
  __shared__ f16 Hs[BM][KH];    // 8 KB
  int t = threadIdx.x;
  int e0 = blockIdx.x * BM;
  int y  = blockIdx.y;
  f16* msgf = y ? msgfB : msgfA;

  {
    int r = t >> 1, q = t & 1;     // 2 threads per edge row
    int ep = perm[e0 + r];
    const f16x8* hsrc = (const f16x8*)(hf + (size_t)ep * KH + q * 16);
    *(f16x8*)&Hs[r][q * 16]     = hsrc[0];
    *(f16x8*)&Hs[r][q * 16 + 8] = hsrc[1];
    int s = srcs[e0 + r];
    const float4* src = (const float4*)(xin + (size_t)s * D + y * 64 + q * 32);
    f16* dst = &Xs[r][q * 32];
#pragma unroll
    for (int c = 0; c < 8; c++) {
      float4 v = src[c];
      f16x4 h4 = {(f16)v.x, (f16)v.y, (f16)v.z, (f16)v.w};
      *(f16x4*)(dst + c * 4) = h4;
    }
  }

  int L = t & 63, w = t >> 6;
  int quad = L >> 4, lm = L & 15;
  int n0 = w * 32;

  const f16* bl = Bp + ((size_t)(y * 64) * D + n0 + lm) * KH + quad * 8;
  const size_t istr = (size_t)D * KH;    // f16 stride per i

  f32x4 acc[8][2];
#pragma unroll
  for (int mt = 0; mt < 8; mt++)
#pragma unroll
    for (int nt = 0; nt < 2; nt++)
      acc[mt][nt] = (f32x4){0.f, 0.f, 0.f, 0.f};

  f16x8 bufA[4][2], bufB[4][2], bufC[4][2];

  // issue one 4-i batch = 8 asm loads (pinned dests, untracked by compiler)
  auto issueB = [&](f16x8 (&buf)[4][2], int basei) {
#pragma unroll
    for (int jj = 0; jj < 4; jj++) {
      const f16* bi = bl + (size_t)(basei + jj) * istr;
      ld16(buf[jj][0], bi);
      ld16(buf[jj][1], bi + 16 * KH);
    }
  };

  // counted wait: keep 16 loads (2 batches) in flight; oldest batch retired
  auto wait16 = [&]() {
    asm volatile("s_waitcnt vmcnt(16)" ::: "memory");
    __builtin_amdgcn_sched_barrier(0);
  };
  auto wait8 = [&]() {
    asm volatile("s_waitcnt vmcnt(8)" ::: "memory");
    __builtin_amdgcn_sched_barrier(0);
  };
  auto wait0 = [&]() {
    asm volatile("s_waitcnt vmcnt(0)" ::: "memory");
    __builtin_amdgcn_sched_barrier(0);
  };

  f16x8 hreg[8];

  auto compute = [&](f16x8 (&buf)[4][2], int ig) {
    f16x4 xv[8];
#pragma unroll
    for (int mt = 0; mt < 8; mt++)
      xv[mt] = *(const f16x4*)&Xs[mt * 16 + lm][ig];
    __builtin_amdgcn_s_setprio(1);
#pragma unroll
    for (int jj = 0; jj < 4; jj++) {
#pragma unroll
      for (int mt = 0; mt < 8; mt++) {
        f16 xs = xv[mt][jj];
        f16x8 xb = {xs, xs, xs, xs, xs, xs, xs, xs};
        f16x8 a = hreg[mt] * xb;
        acc[mt][0] = __builtin_amdgcn_mfma_f32_16x16x32_f16(a, buf[jj][0], acc[mt][0], 0, 0, 0);
        acc[mt][1] = __builtin_amdgcn_mfma_f32_16x16x32_f16(a, buf[jj][1], acc[mt][1], 0, 0, 0);
      }
    }
    __builtin_amdgcn_s_setprio(0);
  };

  __syncthreads();               // Xs/Hs ready; staging counts drain here

#pragma unroll
  for (int mt = 0; mt < 8; mt++)
    hreg[mt] = *(const f16x8*)&Hs[mt * 16 + lm][quad * 8];

  issueB(bufA, 0);               // batch 0 (i  0.. 3)
  issueB(bufB, 4);               // batch 1 (i  4.. 7)
  issueB(bufC, 8);               // batch 2 (i  8..11)  -> 24 loads in flight

  // batches 0..15 (i = 4*batch); loop computes 0..11, issues 3..14
#pragma unroll 1
  for (int gi = 0; gi < 4; gi++) {
    wait16();
    compute(bufA, 12 * gi);
    issueB(bufA, 12 * gi + 12);        // batch 3gi+3
    wait16();
    compute(bufB, 12 * gi + 4);
    issueB(bufB, 12 * gi + 16);        // batch 3gi+4
    wait16();
    compute(bufC, 12 * gi + 8);
    issueB(bufC, 12 * gi + 20);        // batch 3gi+5, max basei = 56 (batch 14)
  }
  wait16();
  compute(bufA, 48);             // batch 12
  issueB(bufA, 60);              // batch 15 (last)
  wait16();
  compute(bufB, 52);             // batch 13
  wait8();
  compute(bufC, 56);             // batch 14
  wait0();
  compute(bufA, 60);             // batch 15 -- all loads drained

  // bias fold: this half handles ig2 = 2y, 2y+1 (uses only this half's x)
  {
    const f16* bb = Bp + (size_t)D * D * KH;
#pragma unroll
    for (int g2 = 0; g2 < 2; g2++) {
      int ig2 = 2 * y + g2;
      const f16* b2l = bb + ((size_t)ig2 * D + n0 + lm) * KH + quad * 8;
      f16x8 b0 = *(const f16x8*)b2l;
      f16x8 b1 = *(const f16x8*)(b2l + 16 * KH);
      int lc = g2 * 32 + quad * 8;
#pragma unroll
      for (int mt = 0; mt < 8; mt++) {
        f16x8 a = *(const f16x8*)&Xs[mt * 16 + lm][lc];
        acc[mt][0] = __builtin_amdgcn_mfma_f32_16x16x32_f16(a, b0, acc[mt][0], 0, 0, 0);
        acc[mt][1] = __builtin_amdgcn_mfma_f32_16x16x32_f16(a, b1, acc[mt][1], 0, 0, 0);
      }
    }
  }

  // C/D: col = lane&15 (+nt*16), row = quad*4 + reg
#pragma unroll
  for (int mt = 0; mt < 8; mt++)
#pragma unroll
    for (int r = 0; r < 4; r++) {
      f16* mg = msgf + (size_t)(e0 + mt * 16 + quad * 4 + r) * D + n0 + lm;
      mg[0]  = (f16)acc[mt][0][r];
      mg[16] = (f16)acc[mt][1][r];
    }
}

// node update: out = (relu?) bias + segmean(msgA+msgB) + x@root (f16 MFMA)
// NBL=16 -> 1024 blocks (4/CU); segmean has 1-deep load-ahead pipeline.
__global__ __launch_bounds__(256) void node_update_kernel(
    const float* __restrict__ xin, const f16* __restrict__ msgA,
    const f16* __restrict__ msgB, const int* __restrict__ rs,
    const f16* __restrict__ Rp, const float* __restrict__ bias,
    float* __restrict__ out, int do_relu) {
  __shared__ f16 Xs[NBL][XST];   // 4.3 KB
  __shared__ float Sls[NBL][D];  // 8.2 KB
  int t = threadIdx.x;
  int nb = blockIdx.x * NBL;

  {
    int r = t >> 4, q = t & 15;  // 16 threads per node row, 8 f32 each
    const float4* src = (const float4*)(xin + (size_t)(nb + r) * D + q * 8);
    f16* dst = &Xs[r][q * 8];
#pragma unroll
    for (int c = 0; c < 2; c++) {
      float4 v = src[c];
      f16x4 h4 = {(f16)v.x, (f16)v.y, (f16)v.z, (f16)v.w};
      *(f16x4*)(dst + c * 4) = h4;
    }
  }
  __syncthreads();

  // segment mean over contiguous sorted msg rows (load-ahead pipeline)
  {
    int nl = t >> 4, o0 = (t & 15) * 8;
    int n = nb + nl;
    int a = rs[n], b = rs[n + 1];
    float sum[8];
#pragma unroll
    for (int j = 0; j < 8; j++) sum[j] = 0.f;
    f16x8 pa, pb;
    if (a < b) {
      pa = *(const f16x8*)(msgA + (size_t)a * D + o0);
      pb = *(const f16x8*)(msgB + (size_t)a * D + o0);
    }
    for (int r = a; r < b; r++) {
      f16x8 ca = pa, cb = pb;
      if (r + 1 < b) {
        pa = *(const f16x8*)(msgA + (size_t)(r + 1) * D + o0);
        pb = *(const f16x8*)(msgB + (size_t)(r + 1) * D + o0);
      }
#pragma unroll
      for (int j = 0; j < 8; j++) sum[j] += (float)ca[j] + (float)cb[j];
    }
    float inv = 1.0f / (float)max(b - a, 1);
#pragma unroll
    for (int j = 0; j < 8; j++) Sls[nl][o0 + j] = sum[j] * inv;
  }
  __syncthreads();

  // x@root via MFMA, K=128 (4 slabs), 16 rows (mt=1)
  int L = t & 63, w = t >> 6;
  int quad = L >> 4, lm = L & 15;
  int n0 = w * 32;
  f32x4 acc[2];
  acc[0] = (f32x4){0.f, 0.f, 0.f, 0.f};
  acc[1] = (f32x4){0.f, 0.f, 0.f, 0.f};
#pragma unroll
  for (int s4 = 0; s4 < 4; s4++) {
    const f16* b2l = Rp + ((size_t)s4 * D + n0 + lm) * KH + quad * 8;
    f16x8 b0 = *(const f16x8*)b2l;
    f16x8 b1 = *(const f16x8*)(b2l + 16 * KH);
    f16x8 a = *(const f16x8*)&Xs[lm][s4 * 32 + quad * 8];
    acc[0] = __builtin_amdgcn_mfma_f32_16x16x32_f16(a, b0, acc[0], 0, 0, 0);
    acc[1] = __builtin_amdgcn_mfma_f32_16x16x32_f16(a, b1, acc[1], 0, 0, 0);
  }
#pragma unroll
  for (int r = 0; r < 4; r++) {
    Sls[quad * 4 + r][n0 + lm] += acc[0][r];
    Sls[quad * 4 + r][n0 + 16 + lm] += acc[1][r];
  }
  __syncthreads();

  {
    int o = t & 127, g = t >> 7;   // g = 0..1, 8 rows each
    float bo = bias[o];
    for (int q = g * 8; q < g * 8 + 8; q++) {
      float v = bo + Sls[q][o];
      out[(size_t)(nb + q) * D + o] = do_relu ? fmaxf(v, 0.0f) : v;
    }
  }
}

extern "C" void kernel_launch(void* const* d_in, const int* in_sizes, int n_in,
                              void* d_out, int out_size, void* d_ws, size_t ws_size,
                              hipStream_t stream) {
  const float* x      = (const float*)d_in[0];
  const int*   ei     = (const int*)d_in[1];
  const float* ea     = (const float*)d_in[2];
  const float* w1_l1  = (const float*)d_in[3];
  const float* b1_l1  = (const float*)d_in[4];
  const float* w1_l2  = (const float*)d_in[5];
  const float* b1_l2  = (const float*)d_in[6];
  const float* w1_rt  = (const float*)d_in[7];
  const float* b1     = (const float*)d_in[8];
  const float* w2_l1  = (const float*)d_in[9];
  const float* b2_l1  = (const float*)d_in[10];
  const float* w2_l2  = (const float*)d_in[11];
  const float* b2_l2  = (const float*)d_in[12];
  const float* w2_rt  = (const float*)d_in[13];
  const float* b2     = (const float*)d_in[14];
  float* out = (float*)d_out;

  const size_t BPSZ = (size_t)D * D * KH + (size_t)D * D + 32768;
  f16* h1f = (f16*)d_ws;
  f16* h2f = h1f + (size_t)N_EDGES * KH;
  f16* Bp1 = h2f + (size_t)N_EDGES * KH;
  f16* Bp2 = Bp1 + BPSZ;
  f16* Rp1 = Bp2 + BPSZ;
  f16* Rp2 = Rp1 + (size_t)D * D;
  int* deg  = (int*)(Rp2 + (size_t)D * D);
  int* rs   = deg + N_NODES;
  int* fill = rs + N_NODES + 128;
  int* perm = fill + N_NODES;
  int* srcs = perm + N_EDGES;
  f16* msgA = (f16*)(srcs + N_EDGES);      // E*D f16 (8.4 MB)
  f16* msgB = msgA + (size_t)N_EDGES * D;  // E*D f16 (8.4 MB)

  hipMemsetAsync(deg, 0, N_NODES * sizeof(int), stream);
  deg_pack_kernel<<<dim3(N_EDGES / 256, 9), 256, 0, stream>>>(
      ei, deg, w1_l2, w2_l2, b1_l2, b2_l2, w1_rt, w2_rt, Bp1, Bp2, Rp1, Rp2,
      ea, w1_l1, b1_l1, w2_l1, b2_l1, h1f, h2f);
  scan_kernel<<<1, 1024, 0, stream>>>(deg, rs, fill);
  scatter_kernel<<<N_EDGES / 256, 256, 0, stream>>>(ei, fill, perm, srcs);

  // layer 1
  msg_mfma_kernel<<<dim3(N_EDGES / BM, 2), 256, 0, stream>>>(x, h1f, Bp1, srcs, perm, msgA, msgB);
  node_update_kernel<<<N_NODES / NBL, 256, 0, stream>>>(x, msgA, msgB, rs, Rp1, b1, out, 1);
  // layer 2
  msg_mfma_kernel<<<dim3(N_EDGES / BM, 2), 256, 0, stream>>>(out, h2f, Bp2, srcs, perm, msgA, msgB);
  node_update_kernel<<<N_NODES / NBL, 256, 0, stream>>>(out, msgA, msgB, rs, Rp2, b2, out, 1);
  // layer 3
  msg_mfma_kernel<<<dim3(N_EDGES / BM, 2), 256, 0, stream>>>(out, h2f, Bp2, srcs, perm, msgA, msgB);
  node_update_kernel<<<N_NODES / NBL, 256, 0, stream>>>(out, msgA, msgB, rs, Rp2, b2, out, 0);
}